// Round 11
// baseline (446.051 us; speedup 1.0000x reference)
//
#include <hip/hip_runtime.h>
#include <hip/hip_fp16.h>

#define N    8192
#define FIN  256
#define FOUT 128
#define BN   64

typedef _Float16 half8 __attribute__((ext_vector_type(8)));
typedef _Float16 half4v __attribute__((ext_vector_type(4)));
typedef float floatx4 __attribute__((ext_vector_type(4)));

// v_exp_f32 computes 2^x directly; __exp2f is not declared in these headers.
__device__ __forceinline__ float exp2_fast(float x) { return __builtin_amdgcn_exp2f(x); }

// Direct global->LDS DMA, 16 B per lane: LDS dest = wave-uniform base (HW adds
// lane*16); global src is per-lane.
__device__ __forceinline__ void gload_lds16(const void* g, void* l) {
    __builtin_amdgcn_global_load_lds(
        (const __attribute__((address_space(1))) void*)g,
        (__attribute__((address_space(3))) void*)l, 16, 0, 0);
}

// ---------------------------------------------------------------------------
// W-prep: frag-major fp16 W for coalesced MFMA B-loads.
// ---------------------------------------------------------------------------
__global__ __launch_bounds__(256)
void wprep_kernel(const float* __restrict__ W0,
                  const float* __restrict__ W1,
                  const float* __restrict__ W2,
                  _Float16* __restrict__ Wf)
{
    int idx  = blockIdx.x * 256 + threadIdx.x;   // 0..12287
    int lane = idx & 63;
    int frag = idx >> 6;
    int w    = frag >> 6;
    int f    = frag & 63;
    int nt   = f >> 3, kc = f & 7;
    int quad = lane >> 4, lo16 = lane & 15;
    const float* Wp = w == 0 ? W0 : (w == 1 ? W1 : W2);
    half8 v;
#pragma unroll
    for (int jj = 0; jj < 8; jj++)
        v[jj] = (_Float16)Wp[(size_t)(kc * 32 + quad * 8 + jj) * FOUT + nt * 16 + lo16];
    *(half8*)&Wf[(size_t)idx * 8] = v;
}

// ---------------------------------------------------------------------------
// H = fp16(log2e * inp@W), H2 = fp16(inp@W2), H3T = fp16((inp@W3)^T).
// (Proven body, unchanged.)
// ---------------------------------------------------------------------------
__global__ __launch_bounds__(256, 2)
void gemm3_kernel(const float* __restrict__ inp,
                  const _Float16* __restrict__ Wf,
                  _Float16* __restrict__ H,
                  _Float16* __restrict__ H2,
                  _Float16* __restrict__ H3T)
{
    const int which = blockIdx.z;
    const int c0    = blockIdx.y * 64;
    const _Float16* Wfw = Wf + (size_t)which * 64 * 64 * 8;
    const int r0 = blockIdx.x * 64;
    const int tid  = threadIdx.x;
    const int wave = tid >> 6;
    const int lane = tid & 63;
    const int lo16 = lane & 15;
    const int quad = lane >> 4;
    const int r = r0 + wave * 16 + lo16;

    half8 a[8];
#pragma unroll
    for (int kc = 0; kc < 8; kc++) {
        const float* p = &inp[(size_t)r * FIN + kc * 32 + quad * 8];
        float4 v0 = *(const float4*)p;
        float4 v1 = *(const float4*)(p + 4);
        a[kc][0] = (_Float16)v0.x; a[kc][1] = (_Float16)v0.y;
        a[kc][2] = (_Float16)v0.z; a[kc][3] = (_Float16)v0.w;
        a[kc][4] = (_Float16)v1.x; a[kc][5] = (_Float16)v1.y;
        a[kc][6] = (_Float16)v1.z; a[kc][7] = (_Float16)v1.w;
    }

    floatx4 acc[4];
#pragma unroll
    for (int i = 0; i < 4; i++) acc[i] = (floatx4){0.f, 0.f, 0.f, 0.f};

#pragma unroll
    for (int kc = 0; kc < 8; kc++)
#pragma unroll
        for (int nt = 0; nt < 4; nt++) {
            int ntg = (c0 >> 4) + nt;
            half8 b = *(const half8*)&Wfw[(((size_t)ntg * 8 + kc) * 64 + lane) * 8];
            acc[nt] = __builtin_amdgcn_mfma_f32_16x16x32_f16(a[kc], b, acc[nt], 0, 0, 0);
        }

    const int arow = wave * 16 + quad * 4;
    if (which < 2) {
        _Float16* outp = which == 0 ? H : H2;
        const float scale = which == 0 ? 1.44269504f : 1.0f;   // log2(e) folded into Q
#pragma unroll
        for (int nt = 0; nt < 4; nt++)
#pragma unroll
            for (int rr = 0; rr < 4; rr++)
                outp[(size_t)(r0 + arow + rr) * FOUT + c0 + nt * 16 + lo16] =
                    (_Float16)(acc[nt][rr] * scale);
    } else {
#pragma unroll
        for (int nt = 0; nt < 4; nt++) {
            half4v v;
#pragma unroll
            for (int rr = 0; rr < 4; rr++) v[rr] = (_Float16)acc[nt][rr];
            *(half4v*)&H3T[(size_t)(c0 + nt * 16 + lo16) * N + r0 + arow] = v;
        }
    }
}

// ---------------------------------------------------------------------------
// Fused repack: blocks [0,512) build Kf (sigma j-permutation baked in),
// blocks [512,1024) build Vf. (Proven, unchanged.)
// ---------------------------------------------------------------------------
__global__ __launch_bounds__(256)
void repackKV_kernel(const _Float16* __restrict__ H2,
                     const _Float16* __restrict__ H3T,
                     _Float16* __restrict__ Kf,
                     _Float16* __restrict__ Vf)
{
    if (blockIdx.x < 512) {
        int idx  = blockIdx.x * 256 + threadIdx.x;
        int lane = idx & 63;
        int frag = idx >> 6;
        int jb = frag >> 4, f = frag & 15;
        int c = f >> 3, ntj = (f >> 2) & 1, kc = f & 3;
        int quad = lane >> 4, lo16 = lane & 15;
        int srcrow = jb * 64 + c * 32 + (lo16 >> 2) * 8 + ntj * 4 + (lo16 & 3);
        half8 v = *(const half8*)&H2[(size_t)srcrow * FOUT + kc * 32 + quad * 8];
        *(half8*)&Kf[(size_t)idx * 8] = v;
    } else {
        int idx  = (blockIdx.x - 512) * 256 + threadIdx.x;
        int lane = idx & 63;
        int frag = idx >> 6;
        int jb = frag >> 4, f = frag & 15, nt = f >> 1, kc = f & 1;
        int quad = lane >> 4, lo16 = lane & 15;
        half8 v = *(const half8*)&H3T[(size_t)(nt * 16 + lo16) * N + jb * 64 + kc * 32 + quad * 8];
        *(half8*)&Vf[(size_t)idx * 8] = v;
    }
}

// ---------------------------------------------------------------------------
// Flash attention, R20: R19 base with the adj stream MOVED OUT of the
// barrier-synchronized loop into a barrier-free PROLOGUE BURST.
//  - Prologue: each wave reads its own 16 rows x 4 groups of adj as 64
//    contiguous 1 KB loads, batched 8-deep (continuous MLP -> BW-bound like
//    the fill kernel), ballots into wave-private LDS ML[wave][g][r][16].
//    Word/bit layout identical to R19 (bit l of word r = col 4l+r).
//  - Main loop: ZERO adj traffic. Masks come from 4 conflict-free LDS reads
//    per iter; KV staging (L2-resident) drains for free under the compute.
//  LDS = 64 KB KV + 16 KB ML = 80 KB -> still 2 blocks/CU (16 waves/CU).
// ---------------------------------------------------------------------------
template<int JS>
__global__ __launch_bounds__(512, 2)
void attn_kernel(const _Float16* __restrict__ Hq,   // [N][128], log2e folded
                 const _Float16* __restrict__ Kf,   // permuted frag-major
                 const _Float16* __restrict__ Vf,   // frag-major
                 const int* __restrict__ adj,       // [N][N]
                 float* __restrict__ OpartT,        // [JS][FOUT][N]
                 float* __restrict__ mpart,         // [JS][N]  (log2 domain)
                 float* __restrict__ lpart)         // [JS][N]
{
    __shared__ __align__(16) _Float16 KV[2][16384];   // [buf][16 K frags | 16 V frags]
    __shared__ unsigned long long ML[8 * 256];        // [wave][(g*4+r)*16 + r16]

    const int tid  = threadIdx.x;        // 0..511
    const int wave = tid >> 6;           // 0..7
    const int lane = tid & 63;
    const int lo16 = lane & 15;
    const int quad = lane >> 4;
    const int qsh  = quad * 2;           // mask shift component
    const int bid  = blockIdx.x;
    const int js   = bid & (JS - 1);     // XCD affinity
    const int ib   = bid / JS;
    const int iw   = ib * 128 + wave * 16;   // this wave's 16-row slice
    const int irow = iw + lo16;              // this lane's i-row
    const int jbeg = js * (N / JS);
    constexpr int NIT = 16;              // (N/JS)/BN
    const int jb0  = jbeg >> 6;

    // Q fragments (B-operand) for this lane's row
    half8 q[4];
#pragma unroll
    for (int kc = 0; kc < 4; kc++)
        q[kc] = *(const half8*)&Hq[(size_t)irow * FOUT + kc * 32 + quad * 8];

    floatx4 O[8];
#pragma unroll
    for (int nt = 0; nt < 8; nt++) O[nt] = (floatx4){0.f, 0.f, 0.f, 0.f};
    float m_s = -1e12f, l_s = 0.f;

    auto STAGE = [&](int nxt, int jbn) {
        const _Float16* gk = Kf + (size_t)jbn * 8192;
        const _Float16* gv = Vf + (size_t)jbn * 8192;
#pragma unroll
        for (int r = 0; r < 2; r++) {
            int goff = (r * 512 + tid) * 8;
            int loff = (r * 512 + wave * 64) * 8;            // wave-uniform base
            gload_lds16(gk + goff, &KV[nxt][loff]);
            gload_lds16(gv + goff, &KV[nxt][8192 + loff]);
        }
    };

    // ---- prologue A: stage KV tile 0 ----
    STAGE(0, jb0);

    // ---- prologue B: barrier-free adj burst -> wave-private mask LDS ----
    // Wave reads rows iw..iw+15, cols jbeg..jbeg+1023 as 64 x 1 KB contiguous
    // loads (8 batches of 8 -> 8 KB/wave continuously in flight). Ballot
    // word b_r: bit l = (col 4l+r != 0). ML[wave][(g*4+r)*16 + r16] = b_r.
    unsigned long long* MLb = &ML[wave * 256];
    {
        const int* ab = adj + (size_t)iw * N + jbeg + lane * 4;
#pragma unroll
        for (int b = 0; b < 8; b++) {
            int4 av[8];
#pragma unroll
            for (int x = 0; x < 8; x++) {
                int r16 = b * 2 + (x >> 2);
                int g   = x & 3;
                av[x] = *(const int4*)(ab + (size_t)r16 * N + g * 256);
            }
#pragma unroll
            for (int x = 0; x < 8; x++) {
                int r16 = b * 2 + (x >> 2);
                int g   = x & 3;
                unsigned long long b0 = __ballot(av[x].x != 0);
                unsigned long long b1 = __ballot(av[x].y != 0);
                unsigned long long b2 = __ballot(av[x].z != 0);
                unsigned long long b3 = __ballot(av[x].w != 0);
                unsigned long long v = lane == 0 ? b0 : (lane == 1 ? b1 : (lane == 2 ? b2 : b3));
                if (lane < 4) MLb[(g * 4 + lane) * 16 + r16] = v;
            }
        }
    }
    __syncthreads();   // KV tile 0 + (wave-local) masks resident

    auto ITER = [&](int it) {
        const int cur = it & 1;
        const int p   = it & 3;          // window within group

        // ---- 1) stage next KV tile (L2-resident; drains under compute) ----
        if (it + 1 < NIT) STAGE(cur ^ 1, jb0 + it + 1);

        // ---- 2) masks from wave-private LDS (4 x ds_read_b64, broadcast
        //         across quads, conflict-free across lo16) ----
        unsigned long long mc[4];
#pragma unroll
        for (int r = 0; r < 4; r++)
            mc[r] = MLb[((it >> 2) * 4 + r) * 16 + lo16];

        const _Float16* kb = &KV[cur][0];
        const _Float16* vb = &KV[cur][8192];

        // ---- 3) S^T = K Q^T : j = c*32 + 8*quad + 4*ntj + r, i = lo16 ----
        floatx4 S[2][2];   // [c][ntj]
#pragma unroll
        for (int c = 0; c < 2; c++)
#pragma unroll
            for (int ntj = 0; ntj < 2; ntj++) {
                S[c][ntj] = (floatx4){0.f, 0.f, 0.f, 0.f};
#pragma unroll
                for (int kc = 0; kc < 4; kc++) {
                    half8 kf = *(const half8*)&kb[(((c * 2 + ntj) * 4 + kc) * 64 + lane) * 8];
                    S[c][ntj] = __builtin_amdgcn_mfma_f32_16x16x32_f16(kf, q[kc], S[c][ntj], 0, 0, 0);
                }
            }

        // ---- 4) online softmax (exp2), in-place lrelu, deferred rescale ----
        float mx = -1e12f;
#pragma unroll
        for (int c = 0; c < 2; c++)
#pragma unroll
            for (int ntj = 0; ntj < 2; ntj++)
#pragma unroll
                for (int r = 0; r < 4; r++) {
                    float e = S[c][ntj][r];
                    e = fmaxf(e, 0.2f * e);          // lrelu (scale-commutes)
                    S[c][ntj][r] = e;
                    mx = fmaxf(mx, e);
                }
        mx = fmaxf(mx, __shfl_xor(mx, 16));
        mx = fmaxf(mx, __shfl_xor(mx, 32));
        if (__any(mx > m_s + 5.75f)) {
            float mn2 = fmaxf(m_s, mx);
            float al = exp2_fast(m_s - mn2);
            m_s = mn2;
            l_s *= al;
#pragma unroll
            for (int nt = 0; nt < 8; nt++)
#pragma unroll
                for (int r = 0; r < 4; r++)
                    O[nt][r] *= al;
        }

        half8 pb[2];       // [c], element jj = ntj*4 + r
        float sum = 0.f;
#pragma unroll
        for (int c = 0; c < 2; c++)
#pragma unroll
            for (int ntj = 0; ntj < 2; ntj++)
#pragma unroll
                for (int r = 0; r < 4; r++) {
                    float e = S[c][ntj][r] - m_s;
                    // bit l = p*16 + c*8 + quad*2 + ntj of word mc[r]
                    bool bit = (mc[r] >> (p * 16 + c * 8 + ntj + qsh)) & 1ull;
                    float pp = bit ? exp2_fast(e) : 0.f;
                    sum += pp;
                    pb[c][ntj * 4 + r] = (_Float16)pp;
                }
        sum += __shfl_xor(sum, 16);
        sum += __shfl_xor(sum, 32);
        l_s += sum;

        // ---- 5) O^T += V^T P^T ----
#pragma unroll
        for (int c = 0; c < 2; c++)
#pragma unroll
            for (int nt = 0; nt < 8; nt++) {
                half8 vf = *(const half8*)&vb[((nt * 2 + c) * 64 + lane) * 8];
                O[nt] = __builtin_amdgcn_mfma_f32_16x16x32_f16(vf, pb[c], O[nt], 0, 0, 0);
            }

        // ---- 6) single barrier: drains this iter's KV DMA ----
        __syncthreads();
    };

#pragma unroll
    for (int it = 0; it < NIT; it++)
        ITER(it);

    // epilogue: O^T[f][i] -> OpartT[js][f][i] (unnormalized) + (m,l)
#pragma unroll
    for (int nt = 0; nt < 8; nt++)
#pragma unroll
        for (int r = 0; r < 4; r++) {
            int f = nt * 16 + quad * 4 + r;
            OpartT[((size_t)js * FOUT + f) * N + irow] = O[nt][r];
        }
    if (quad == 0) {
        mpart[js * N + irow] = m_s;
        lpart[js * N + irow] = l_s;
    }
}

// ---------------------------------------------------------------------------
// Combine: f-major partials -> normalize -> ELU -> out[i][f].
// m is in log2 domain -> exp2 for the cross-partial weights.
// ---------------------------------------------------------------------------
template<int JS>
__global__ __launch_bounds__(256)
void combine_kernel(const float* __restrict__ OpartT,
                    const float* __restrict__ mpart,
                    const float* __restrict__ lpart,
                    float* __restrict__ out)
{
    int idx = blockIdx.x * 256 + threadIdx.x;   // 128 f x 2048 i-groups
    int f  = idx >> 11;
    int i4 = (idx & 2047) << 2;

    float4 M = {-3e38f, -3e38f, -3e38f, -3e38f};
    float4 m[JS];
#pragma unroll
    for (int s = 0; s < JS; s++) {
        m[s] = *(const float4*)&mpart[s * N + i4];
        M.x = fmaxf(M.x, m[s].x); M.y = fmaxf(M.y, m[s].y);
        M.z = fmaxf(M.z, m[s].z); M.w = fmaxf(M.w, m[s].w);
    }
    float4 L = {0.f, 0.f, 0.f, 0.f};
    float4 o = {0.f, 0.f, 0.f, 0.f};
#pragma unroll
    for (int s = 0; s < JS; s++) {
        float4 l = *(const float4*)&lpart[s * N + i4];
        float4 w;
        w.x = exp2_fast(m[s].x - M.x); w.y = exp2_fast(m[s].y - M.y);
        w.z = exp2_fast(m[s].z - M.z); w.w = exp2_fast(m[s].w - M.w);
        L.x += l.x * w.x; L.y += l.y * w.y;
        L.z += l.z * w.z; L.w += l.w * w.w;
        float4 v = *(const float4*)&OpartT[((size_t)s * FOUT + f) * N + i4];
        o.x += w.x * v.x; o.y += w.y * v.y;
        o.z += w.z * v.z; o.w += w.w * v.w;
    }
    float r0 = o.x / L.x, r1 = o.y / L.y, r2 = o.z / L.z, r3 = o.w / L.w;
    out[(size_t)(i4 + 0) * FOUT + f] = r0 > 0.f ? r0 : __expf(r0) - 1.f;
    out[(size_t)(i4 + 1) * FOUT + f] = r1 > 0.f ? r1 : __expf(r1) - 1.f;
    out[(size_t)(i4 + 2) * FOUT + f] = r2 > 0.f ? r2 : __expf(r2) - 1.f;
    out[(size_t)(i4 + 3) * FOUT + f] = r3 > 0.f ? r3 : __expf(r3) - 1.f;
}

// ---------------------------------------------------------------------------
extern "C" void kernel_launch(void* const* d_in, const int* in_sizes, int n_in,
                              void* d_out, int out_size, void* d_ws, size_t ws_size,
                              hipStream_t stream) {
    const float* inp = (const float*)d_in[0];
    const int*   adj = (const int*)d_in[1];
    const float* W0  = (const float*)d_in[2];
    const float* W1  = (const float*)d_in[3];
    const float* W2  = (const float*)d_in[4];
    float* out = (float*)d_out;

    constexpr int JS = 8;
    char* ws = (char*)d_ws;
    _Float16* H    = (_Float16*)(ws);                          // 2 MB
    _Float16* H2   = (_Float16*)(ws + (2u << 20));             // 2 MB
    _Float16* H3T  = (_Float16*)(ws + (4u << 20));             // 2 MB
    _Float16* Wf   = (_Float16*)(ws + (6u << 20));             // 192 KB
    _Float16* Kf   = (_Float16*)(ws + (7u << 20));             // 2 MB
    _Float16* Vf   = (_Float16*)(ws + (9u << 20));             // 2 MB
    float* OpartT  = (float*)(ws + (11u << 20));               // 32 MB
    float* mpart   = (float*)(ws + (43u << 20));               // 256 KB
    float* lpart   = (float*)(ws + (43u << 20) + (size_t)JS * N * sizeof(float));

    wprep_kernel<<<48, 256, 0, stream>>>(W0, W1, W2, Wf);
    gemm3_kernel<<<dim3(N / 64, 2, 3), 256, 0, stream>>>(inp, Wf, H, H2, H3T);
    repackKV_kernel<<<1024, 256, 0, stream>>>(H2, H3T, Kf, Vf);
    attn_kernel<JS><<<(N / 128) * JS, 512, 0, stream>>>(H, Kf, Vf, adj, OpartT, mpart, lpart);
    combine_kernel<JS><<<(FOUT * (N / 4)) / 256, 256, 0, stream>>>(OpartT, mpart, lpart, out);
}

// Round 12
// 410.310 us; speedup vs baseline: 1.0871x; 1.0871x over previous
//
#include <hip/hip_runtime.h>
#include <hip/hip_fp16.h>

#define N    8192
#define FIN  256
#define FOUT 128
#define BN   64

typedef _Float16 half8 __attribute__((ext_vector_type(8)));
typedef _Float16 half4v __attribute__((ext_vector_type(4)));
typedef float floatx4 __attribute__((ext_vector_type(4)));

// v_exp_f32 computes 2^x directly; __exp2f is not declared in these headers.
__device__ __forceinline__ float exp2_fast(float x) { return __builtin_amdgcn_exp2f(x); }

// Direct global->LDS DMA, 16 B per lane: LDS dest = wave-uniform base (HW adds
// lane*16); global src is per-lane.
__device__ __forceinline__ void gload_lds16(const void* g, void* l) {
    __builtin_amdgcn_global_load_lds(
        (const __attribute__((address_space(1))) void*)g,
        (__attribute__((address_space(3))) void*)l, 16, 0, 0);
}

// ---------------------------------------------------------------------------
// W-prep: frag-major fp16 W for coalesced MFMA B-loads.
// ---------------------------------------------------------------------------
__global__ __launch_bounds__(256)
void wprep_kernel(const float* __restrict__ W0,
                  const float* __restrict__ W1,
                  const float* __restrict__ W2,
                  _Float16* __restrict__ Wf)
{
    int idx  = blockIdx.x * 256 + threadIdx.x;   // 0..12287
    int lane = idx & 63;
    int frag = idx >> 6;
    int w    = frag >> 6;
    int f    = frag & 63;
    int nt   = f >> 3, kc = f & 7;
    int quad = lane >> 4, lo16 = lane & 15;
    const float* Wp = w == 0 ? W0 : (w == 1 ? W1 : W2);
    half8 v;
#pragma unroll
    for (int jj = 0; jj < 8; jj++)
        v[jj] = (_Float16)Wp[(size_t)(kc * 32 + quad * 8 + jj) * FOUT + nt * 16 + lo16];
    *(half8*)&Wf[(size_t)idx * 8] = v;
}

// ---------------------------------------------------------------------------
// H = fp16(log2e * inp@W), H2 = fp16(inp@W2), H3T = fp16((inp@W3)^T).
// (Proven body, unchanged.)
// ---------------------------------------------------------------------------
__global__ __launch_bounds__(256, 2)
void gemm3_kernel(const float* __restrict__ inp,
                  const _Float16* __restrict__ Wf,
                  _Float16* __restrict__ H,
                  _Float16* __restrict__ H2,
                  _Float16* __restrict__ H3T)
{
    const int which = blockIdx.z;
    const int c0    = blockIdx.y * 64;
    const _Float16* Wfw = Wf + (size_t)which * 64 * 64 * 8;
    const int r0 = blockIdx.x * 64;
    const int tid  = threadIdx.x;
    const int wave = tid >> 6;
    const int lane = tid & 63;
    const int lo16 = lane & 15;
    const int quad = lane >> 4;
    const int r = r0 + wave * 16 + lo16;

    half8 a[8];
#pragma unroll
    for (int kc = 0; kc < 8; kc++) {
        const float* p = &inp[(size_t)r * FIN + kc * 32 + quad * 8];
        float4 v0 = *(const float4*)p;
        float4 v1 = *(const float4*)(p + 4);
        a[kc][0] = (_Float16)v0.x; a[kc][1] = (_Float16)v0.y;
        a[kc][2] = (_Float16)v0.z; a[kc][3] = (_Float16)v0.w;
        a[kc][4] = (_Float16)v1.x; a[kc][5] = (_Float16)v1.y;
        a[kc][6] = (_Float16)v1.z; a[kc][7] = (_Float16)v1.w;
    }

    floatx4 acc[4];
#pragma unroll
    for (int i = 0; i < 4; i++) acc[i] = (floatx4){0.f, 0.f, 0.f, 0.f};

#pragma unroll
    for (int kc = 0; kc < 8; kc++)
#pragma unroll
        for (int nt = 0; nt < 4; nt++) {
            int ntg = (c0 >> 4) + nt;
            half8 b = *(const half8*)&Wfw[(((size_t)ntg * 8 + kc) * 64 + lane) * 8];
            acc[nt] = __builtin_amdgcn_mfma_f32_16x16x32_f16(a[kc], b, acc[nt], 0, 0, 0);
        }

    const int arow = wave * 16 + quad * 4;
    if (which < 2) {
        _Float16* outp = which == 0 ? H : H2;
        const float scale = which == 0 ? 1.44269504f : 1.0f;   // log2(e) folded into Q
#pragma unroll
        for (int nt = 0; nt < 4; nt++)
#pragma unroll
            for (int rr = 0; rr < 4; rr++)
                outp[(size_t)(r0 + arow + rr) * FOUT + c0 + nt * 16 + lo16] =
                    (_Float16)(acc[nt][rr] * scale);
    } else {
#pragma unroll
        for (int nt = 0; nt < 4; nt++) {
            half4v v;
#pragma unroll
            for (int rr = 0; rr < 4; rr++) v[rr] = (_Float16)acc[nt][rr];
            *(half4v*)&H3T[(size_t)(c0 + nt * 16 + lo16) * N + r0 + arow] = v;
        }
    }
}

// ---------------------------------------------------------------------------
// Fused repack: blocks [0,512) build Kf (sigma j-permutation baked in),
// blocks [512,1024) build Vf. (Proven, unchanged.)
// ---------------------------------------------------------------------------
__global__ __launch_bounds__(256)
void repackKV_kernel(const _Float16* __restrict__ H2,
                     const _Float16* __restrict__ H3T,
                     _Float16* __restrict__ Kf,
                     _Float16* __restrict__ Vf)
{
    if (blockIdx.x < 512) {
        int idx  = blockIdx.x * 256 + threadIdx.x;
        int lane = idx & 63;
        int frag = idx >> 6;
        int jb = frag >> 4, f = frag & 15;
        int c = f >> 3, ntj = (f >> 2) & 1, kc = f & 3;
        int quad = lane >> 4, lo16 = lane & 15;
        int srcrow = jb * 64 + c * 32 + (lo16 >> 2) * 8 + ntj * 4 + (lo16 & 3);
        half8 v = *(const half8*)&H2[(size_t)srcrow * FOUT + kc * 32 + quad * 8];
        *(half8*)&Kf[(size_t)idx * 8] = v;
    } else {
        int idx  = (blockIdx.x - 512) * 256 + threadIdx.x;
        int lane = idx & 63;
        int frag = idx >> 6;
        int jb = frag >> 4, f = frag & 15, nt = f >> 1, kc = f & 1;
        int quad = lane >> 4, lo16 = lane & 15;
        half8 v = *(const half8*)&H3T[(size_t)(nt * 16 + lo16) * N + jb * 64 + kc * 32 + quad * 8];
        *(half8*)&Vf[(size_t)idx * 8] = v;
    }
}

// ---------------------------------------------------------------------------
// Flash attention, R21 == R19 (proven 412.9 best: 512-thread / 8-wave blocks,
// contiguous 1 KB whole-row adj reads + interleaved ballots with one-iter
// slack, gload_lds KV double-buffer, exp2 softmax, deferred rescale) with ONE
// delta: the epilogue NORMALIZES O by 1/l_s and stores fp16 partials,
// halving OpartT traffic (32 MB -> 16 MB write; combine reads halve too).
// ---------------------------------------------------------------------------
template<int JS>
__global__ __launch_bounds__(512, 2)
void attn_kernel(const _Float16* __restrict__ Hq,   // [N][128], log2e folded
                 const _Float16* __restrict__ Kf,   // permuted frag-major
                 const _Float16* __restrict__ Vf,   // frag-major
                 const int* __restrict__ adj,       // [N][N]
                 _Float16* __restrict__ OpartT,     // [JS][FOUT][N]  normalized fp16
                 float* __restrict__ mpart,         // [JS][N]  (log2 domain)
                 float* __restrict__ lpart)         // [JS][N]
{
    __shared__ __align__(16) _Float16 KV[2][16384];   // [buf][16 K frags | 16 V frags]

    const int tid  = threadIdx.x;        // 0..511
    const int wave = tid >> 6;           // 0..7
    const int lane = tid & 63;
    const int lo16 = lane & 15;
    const int quad = lane >> 4;
    const int qsh  = quad * 2;           // mask shift component
    const int bid  = blockIdx.x;
    const int js   = bid & (JS - 1);     // XCD affinity
    const int ib   = bid / JS;
    const int iw   = ib * 128 + wave * 16;   // this wave's 16-row slice
    const int irow = iw + lo16;              // this lane's i-row
    const int jbeg = js * (N / JS);
    constexpr int NIT = 16;              // (N/JS)/BN
    const int jb0  = jbeg >> 6;

    // Q fragments (B-operand) for this lane's row
    half8 q[4];
#pragma unroll
    for (int kc = 0; kc < 4; kc++)
        q[kc] = *(const half8*)&Hq[(size_t)irow * FOUT + kc * 32 + quad * 8];

    floatx4 O[8];
#pragma unroll
    for (int nt = 0; nt < 8; nt++) O[nt] = (floatx4){0.f, 0.f, 0.f, 0.f};
    float m_s = -1e12f, l_s = 0.f;

    // whole-row adj reads: wave reads row (iw+x), 1 KB span (4 windows),
    // lane l -> cols g*256 + 4l .. 4l+3. Perfectly coalesced dwordx4.
    const int* arow_base = adj + (size_t)iw * N + jbeg + lane * 4;

    unsigned long long mA[4], mB[4];     // mask ping-pong: word r, bit l = col 4l+r

    auto STAGE = [&](int nxt, int jbn) {
        const _Float16* gk = Kf + (size_t)jbn * 8192;
        const _Float16* gv = Vf + (size_t)jbn * 8192;
#pragma unroll
        for (int r = 0; r < 2; r++) {
            int goff = (r * 512 + tid) * 8;
            int loff = (r * 512 + wave * 64) * 8;            // wave-uniform base
            gload_lds16(gk + goff, &KV[nxt][loff]);
            gload_lds16(gv + goff, &KV[nxt][8192 + loff]);
        }
    };

    // ballot 4 rows' loaded values into mask words (select by lo16==row)
    auto BALLOT4 = [&](unsigned long long (&mn)[4], int p,
                       const int4& a0, const int4& a1, const int4& a2, const int4& a3) {
#pragma unroll
        for (int qq = 0; qq < 4; qq++) {
            const int4& a = (qq == 0) ? a0 : (qq == 1) ? a1 : (qq == 2) ? a2 : a3;
            unsigned long long b0 = __ballot(a.x != 0);
            unsigned long long b1 = __ballot(a.y != 0);
            unsigned long long b2 = __ballot(a.z != 0);
            unsigned long long b3 = __ballot(a.w != 0);
            bool sel = (lo16 == p * 4 + qq);
            mn[0] = sel ? b0 : mn[0];
            mn[1] = sel ? b1 : mn[1];
            mn[2] = sel ? b2 : mn[2];
            mn[3] = sel ? b3 : mn[3];
        }
    };

    // prologue: stage KV tile 0; build group-0 masks (16 contiguous row reads)
    STAGE(0, jb0);
#pragma unroll
    for (int p = 0; p < 4; p++) {
        const int* rb = arow_base;                       // group 0 base
        int4 a0 = *(const int4*)(rb + (size_t)(p * 4 + 0) * N);
        int4 a1 = *(const int4*)(rb + (size_t)(p * 4 + 1) * N);
        int4 a2 = *(const int4*)(rb + (size_t)(p * 4 + 2) * N);
        int4 a3 = *(const int4*)(rb + (size_t)(p * 4 + 3) * N);
        BALLOT4(mA, p, a0, a1, a2, a3);
    }
    __syncthreads();   // drains vmcnt(0): tile 0 resident

    auto ITER = [&](int it, int p, unsigned long long (&mc)[4],
                    unsigned long long (&mn)[4], bool buildNext, int gnext) {
        const int cur = it & 1;

        // ---- 1) issue next-group row loads (4 contiguous 1 KB reads) ----
        int4 a0, a1, a2, a3;
        if (buildNext) {
            const int* rb = arow_base + gnext * 256;
            a0 = *(const int4*)(rb + (size_t)(p * 4 + 0) * N);
            a1 = *(const int4*)(rb + (size_t)(p * 4 + 1) * N);
            a2 = *(const int4*)(rb + (size_t)(p * 4 + 2) * N);
            a3 = *(const int4*)(rb + (size_t)(p * 4 + 3) * N);
        }
        // ---- 2) stage next KV tile ----
        if (it + 1 < NIT) STAGE(cur ^ 1, jb0 + it + 1);

        const _Float16* kb = &KV[cur][0];
        const _Float16* vb = &KV[cur][8192];

        // ---- 3) S^T = K Q^T : j = c*32 + 8*quad + 4*ntj + r, i = lo16 ----
        floatx4 S[2][2];   // [c][ntj]
#pragma unroll
        for (int c = 0; c < 2; c++)
#pragma unroll
            for (int ntj = 0; ntj < 2; ntj++) {
                S[c][ntj] = (floatx4){0.f, 0.f, 0.f, 0.f};
#pragma unroll
                for (int kc = 0; kc < 4; kc++) {
                    half8 kf = *(const half8*)&kb[(((c * 2 + ntj) * 4 + kc) * 64 + lane) * 8];
                    S[c][ntj] = __builtin_amdgcn_mfma_f32_16x16x32_f16(kf, q[kc], S[c][ntj], 0, 0, 0);
                }
            }

        // ---- 4) online softmax (exp2), in-place lrelu, deferred rescale ----
        float mx = -1e12f;
#pragma unroll
        for (int c = 0; c < 2; c++)
#pragma unroll
            for (int ntj = 0; ntj < 2; ntj++)
#pragma unroll
                for (int r = 0; r < 4; r++) {
                    float e = S[c][ntj][r];
                    e = fmaxf(e, 0.2f * e);          // lrelu (scale-commutes)
                    S[c][ntj][r] = e;
                    mx = fmaxf(mx, e);
                }
        mx = fmaxf(mx, __shfl_xor(mx, 16));
        mx = fmaxf(mx, __shfl_xor(mx, 32));
        if (__any(mx > m_s + 5.75f)) {
            float mn2 = fmaxf(m_s, mx);
            float al = exp2_fast(m_s - mn2);
            m_s = mn2;
            l_s *= al;
#pragma unroll
            for (int nt = 0; nt < 8; nt++)
#pragma unroll
                for (int r = 0; r < 4; r++)
                    O[nt][r] *= al;
        }

        half8 pb[2];       // [c], element jj = ntj*4 + r
        float sum = 0.f;
#pragma unroll
        for (int c = 0; c < 2; c++)
#pragma unroll
            for (int ntj = 0; ntj < 2; ntj++)
#pragma unroll
                for (int r = 0; r < 4; r++) {
                    float e = S[c][ntj][r] - m_s;
                    // bit l = p*16 + c*8 + quad*2 + ntj of word mc[r]
                    bool bit = (mc[r] >> (p * 16 + c * 8 + ntj + qsh)) & 1ull;
                    float pp = bit ? exp2_fast(e) : 0.f;
                    sum += pp;
                    pb[c][ntj * 4 + r] = (_Float16)pp;
                }
        sum += __shfl_xor(sum, 16);
        sum += __shfl_xor(sum, 32);
        l_s += sum;

        // ---- 5) O^T += V^T P^T ----
#pragma unroll
        for (int c = 0; c < 2; c++)
#pragma unroll
            for (int nt = 0; nt < 8; nt++) {
                half8 vf = *(const half8*)&vb[((nt * 2 + c) * 64 + lane) * 8];
                O[nt] = __builtin_amdgcn_mfma_f32_16x16x32_f16(vf, pb[c], O[nt], 0, 0, 0);
            }

        // ---- 6) ballot the row loads issued at step 1 (full iter of slack)
        if (buildNext) BALLOT4(mn, p, a0, a1, a2, a3);

        // ---- 7) single barrier: drains this iter's DMA + row loads ----
        __syncthreads();
    };

    // main loop: 4 groups x 4 windows; masks ping-pong mA <-> mB
#pragma unroll
    for (int g = 0; g < 4; g++) {
#pragma unroll
        for (int p = 0; p < 4; p++) {
            int it = g * 4 + p;
            if (g & 1) ITER(it, p, mB, mA, g < 3, g + 1);
            else       ITER(it, p, mA, mB, g < 3, g + 1);
        }
    }

    // epilogue: normalized fp16 partials. O_norm = O / l_s is a convex
    // combination of V rows (|V| ~ O(4)) -> comfortably fp16.
    const float linv = l_s > 0.f ? 1.f / l_s : 0.f;
#pragma unroll
    for (int nt = 0; nt < 8; nt++)
#pragma unroll
        for (int r = 0; r < 4; r++) {
            int f = nt * 16 + quad * 4 + r;
            OpartT[((size_t)js * FOUT + f) * N + irow] = (_Float16)(O[nt][r] * linv);
        }
    if (quad == 0) {
        mpart[js * N + irow] = m_s;
        lpart[js * N + irow] = l_s;
    }
}

// ---------------------------------------------------------------------------
// Combine: normalized fp16 partials -> weight by w_s*l_s -> ELU -> out[i][f].
// m is in log2 domain -> exp2 for the cross-partial weights. Math identical
// to the fp32-unnormalized version: out = sum(w*l*O_norm) / sum(w*l).
// ---------------------------------------------------------------------------
template<int JS>
__global__ __launch_bounds__(256)
void combine_kernel(const _Float16* __restrict__ OpartT,
                    const float* __restrict__ mpart,
                    const float* __restrict__ lpart,
                    float* __restrict__ out)
{
    int idx = blockIdx.x * 256 + threadIdx.x;   // 128 f x 2048 i-groups
    int f  = idx >> 11;
    int i4 = (idx & 2047) << 2;

    float4 M = {-3e38f, -3e38f, -3e38f, -3e38f};
    float4 m[JS];
#pragma unroll
    for (int s = 0; s < JS; s++) {
        m[s] = *(const float4*)&mpart[s * N + i4];
        M.x = fmaxf(M.x, m[s].x); M.y = fmaxf(M.y, m[s].y);
        M.z = fmaxf(M.z, m[s].z); M.w = fmaxf(M.w, m[s].w);
    }
    float4 L = {0.f, 0.f, 0.f, 0.f};
    float4 o = {0.f, 0.f, 0.f, 0.f};
#pragma unroll
    for (int s = 0; s < JS; s++) {
        float4 l = *(const float4*)&lpart[s * N + i4];
        float4 w;   // w_s * l_s
        w.x = exp2_fast(m[s].x - M.x) * l.x; w.y = exp2_fast(m[s].y - M.y) * l.y;
        w.z = exp2_fast(m[s].z - M.z) * l.z; w.w = exp2_fast(m[s].w - M.w) * l.w;
        L.x += w.x; L.y += w.y; L.z += w.z; L.w += w.w;
        half4v vh = *(const half4v*)&OpartT[((size_t)s * FOUT + f) * N + i4];
        o.x += w.x * (float)vh[0]; o.y += w.y * (float)vh[1];
        o.z += w.z * (float)vh[2]; o.w += w.w * (float)vh[3];
    }
    float r0 = o.x / L.x, r1 = o.y / L.y, r2 = o.z / L.z, r3 = o.w / L.w;
    out[(size_t)(i4 + 0) * FOUT + f] = r0 > 0.f ? r0 : __expf(r0) - 1.f;
    out[(size_t)(i4 + 1) * FOUT + f] = r1 > 0.f ? r1 : __expf(r1) - 1.f;
    out[(size_t)(i4 + 2) * FOUT + f] = r2 > 0.f ? r2 : __expf(r2) - 1.f;
    out[(size_t)(i4 + 3) * FOUT + f] = r3 > 0.f ? r3 : __expf(r3) - 1.f;
}

// ---------------------------------------------------------------------------
extern "C" void kernel_launch(void* const* d_in, const int* in_sizes, int n_in,
                              void* d_out, int out_size, void* d_ws, size_t ws_size,
                              hipStream_t stream) {
    const float* inp = (const float*)d_in[0];
    const int*   adj = (const int*)d_in[1];
    const float* W0  = (const float*)d_in[2];
    const float* W1  = (const float*)d_in[3];
    const float* W2  = (const float*)d_in[4];
    float* out = (float*)d_out;

    constexpr int JS = 8;
    char* ws = (char*)d_ws;
    _Float16* H    = (_Float16*)(ws);                          // 2 MB
    _Float16* H2   = (_Float16*)(ws + (2u << 20));             // 2 MB
    _Float16* H3T  = (_Float16*)(ws + (4u << 20));             // 2 MB
    _Float16* Wf   = (_Float16*)(ws + (6u << 20));             // 192 KB
    _Float16* Kf   = (_Float16*)(ws + (7u << 20));             // 2 MB
    _Float16* Vf   = (_Float16*)(ws + (9u << 20));             // 2 MB
    _Float16* OpartT = (_Float16*)(ws + (11u << 20));          // 16 MB (fp16 normalized)
    float* mpart   = (float*)(ws + (43u << 20));               // 256 KB
    float* lpart   = (float*)(ws + (43u << 20) + (size_t)JS * N * sizeof(float));

    wprep_kernel<<<48, 256, 0, stream>>>(W0, W1, W2, Wf);
    gemm3_kernel<<<dim3(N / 64, 2, 3), 256, 0, stream>>>(inp, Wf, H, H2, H3T);
    repackKV_kernel<<<1024, 256, 0, stream>>>(H2, H3T, Kf, Vf);
    attn_kernel<JS><<<(N / 128) * JS, 512, 0, stream>>>(H, Kf, Vf, adj, OpartT, mpart, lpart);
    combine_kernel<JS><<<(FOUT * (N / 4)) / 256, 256, 0, stream>>>(OpartT, mpart, lpart, out);
}